// Round 1
// 316.998 us; speedup vs baseline: 1.0431x; 1.0431x over previous
//
#include <hip/hip_runtime.h>

#define EMB 300
#define HID 10
#define BATCH 256
#define SEQ 512
#define G3 (3 * HID)          // 30
#define NKT 10                // k-tiles of 32 (tile 9 offset 268, masked weights)
#define XP 36                 // xs row stride (floats): 16B-aligned, 2-way banks
#define WST 328               // LDS weight row stride (shorts) = 656 B -> 2-way banks
#define PFD 4

typedef __attribute__((ext_vector_type(8))) short short8;   // 8 bf16 = 4 VGPRs
typedef __attribute__((ext_vector_type(4))) float f32x4;    // MFMA C/D

__device__ __forceinline__ float fsig(float x) {
    float e = __builtin_amdgcn_exp2f(-1.4426950408889634f * x);
    return __builtin_amdgcn_rcpf(1.0f + e);
}
__device__ __forceinline__ float ftanh(float x) {
    float e = __builtin_amdgcn_exp2f(2.8853900817779268f * x);
    return fmaf(-2.0f, __builtin_amdgcn_rcpf(1.0f + e), 1.0f);
}
__device__ __forceinline__ float rdlane(float v, int lane) {
    return __int_as_float(__builtin_amdgcn_readlane(__float_as_int(v), lane));
}
__device__ __forceinline__ short bf16_hi(float f) {
    return (short)(__float_as_uint(f) >> 16);
}
__device__ __forceinline__ float bf16_tof(short h) {
    return __uint_as_float(((unsigned)(unsigned short)h) << 16);
}

// ---------------------------------------------------------------------------
// Fully fused bi-GRU + head: one block per batch, zero workspace.
//  Phase A: gi[512][32] -> LDS via split-bf16 MFMA (weights pre-split in LDS,
//           x staged with a 2-tile-deep register prefetch pipeline).
//  Phase B: backward single-step on spare lanes, then wave-0 forward scan
//           (identical math to the verified 4-kernel version).
// ---------------------------------------------------------------------------
__global__ __launch_bounds__(256) void k_fused(
    const float* __restrict__ x,
    const float* __restrict__ w_ih_f, const float* __restrict__ b_ih_f,
    const float* __restrict__ w_hh_f, const float* __restrict__ b_hh_f,
    const float* __restrict__ w_ih_b, const float* __restrict__ b_ih_b,
    const float* __restrict__ b_hh_b,
    const float* __restrict__ w_lin, const float* __restrict__ b_lin,
    float* __restrict__ out)
{
    __shared__ float gs[SEQ * 32];        // 64 KB: this batch's gi
    __shared__ short wsh[32 * WST];       // 20.5 KB: split-bf16 hi
    __shared__ short wsl[32 * WST];       // 20.5 KB: split-bf16 lo
    __shared__ float xs[2 * 64 * XP];     // 18 KB: x staging, double-buffered
    __shared__ float gsum[G3];
    __shared__ float hbs[HID];
    // total ~126 KB -> 1 block/CU (4 waves, 1 wave/SIMD; full VGPR budget)

    const int b = blockIdx.x;
    const int t = threadIdx.x;
    const int wave = t >> 6, lane = t & 63;
    const int m = lane & 15, q = lane >> 4;

    const float* __restrict__ xb = x + (size_t)b * SEQ * EMB;

    // staging roles: 8 threads per row, one float4 each (128 B dense per row)
    const int srow = t >> 3;              // 0..31
    const int spiece = (t & 7) * 4;       // 0..28
    const float* __restrict__ xr = xb + (size_t)srow * EMB + spiece;

    // ---- prologue: issue x tiles 0 and 1 early (2-deep prefetch, ~16 KB/CU
    //      in flight >= BW*latency requirement)
    float4 raA = *(const float4*)(xr);              // tile (c=0,kt=0), k0=0
    float4 rbA = *(const float4*)(xr + 32 * EMB);
    float4 raB = *(const float4*)(xr + 32);         // tile (c=0,kt=1), k0=32
    float4 rbB = *(const float4*)(xr + 32 * EMB + 32);

    // ---- per-block weight prep into LDS (same padded k-tiled split-bf16
    //      layout as the old k_prep; rows 30,31 zeroed; tile 9 = cols 268..299
    //      live only ki>=20). w_ih_f is 36 KB -> L2-hot across 256 blocks.
#pragma unroll 8
    for (int i = t; i < 32 * 320; i += 256) {
        const int g = i / 320, kk = i - g * 320;
        const int kt_ = kk >> 5, ki = kk & 31;
        const int k = (kt_ < 9) ? kk : 268 + ki;
        const bool live = (g < G3) && ((kt_ < 9) || (ki >= 20));
        const float v = live ? w_ih_f[g * EMB + k] : 0.0f;
        const short hi = bf16_hi(v);
        wsh[g * WST + kk] = hi;
        wsl[g * WST + kk] = bf16_hi(v - bf16_tof(hi));
    }

    const int rloc = wave * 16 + m;
    const float bias0 = b_ih_f[m];
    const float bias1 = (16 + m < G3) ? b_ih_f[16 + m] : 0.0f;
    const int wrow0 = m * WST;
    const int wrow1 = (16 + m) * WST;

    float* __restrict__ xs0 = xs + srow * XP + spiece;
    float* __restrict__ xs1 = xs + (32 + srow) * XP + spiece;

    // ---- Phase A: 8 chunks x 10 k-tiles. buf parity = kt&1 (10 is even).
    for (int c = 0; c < 8; ++c) {
        f32x4 acc0 = {bias0, bias0, bias0, bias0};
        f32x4 acc1 = {bias1, bias1, bias1, bias1};
#pragma unroll
        for (int kt = 0; kt < NKT; ++kt) {
            const int bofs = (kt & 1) * (64 * XP);
            // store the tile loaded 2 iterations ago, then re-issue its regs
            if ((kt & 1) == 0) {
                *(float4*)(xs0 + bofs) = raA;
                *(float4*)(xs1 + bofs) = rbA;
            } else {
                *(float4*)(xs0 + bofs) = raB;
                *(float4*)(xs1 + bofs) = rbB;
            }
            {   // issue tile tau+2 (compile-time nk/nc in the unrolled body)
                int nc = c, nk = kt + 2;
                if (nk >= NKT) { nk -= NKT; nc++; }
                if (nc < 8) {
                    const int k0 = (nk < 9) ? nk * 32 : 268;   // in-row, never OOB
                    const float* p = xr + (size_t)nc * (64 * EMB) + k0;
                    if ((kt & 1) == 0) {
                        raA = *(const float4*)p;
                        rbA = *(const float4*)(p + 32 * EMB);
                    } else {
                        raB = *(const float4*)p;
                        rbB = *(const float4*)(p + 32 * EMB);
                    }
                }
            }
            __syncthreads();                       // one barrier per tile
            const float* fp = xs + bofs + rloc * XP + q * 8;
            const float4 xa = *(const float4*)fp;
            const float4 xc = *(const float4*)(fp + 4);
            const float av[8] = {xa.x, xa.y, xa.z, xa.w, xc.x, xc.y, xc.z, xc.w};
            short8 ah, al;
#pragma unroll
            for (int jj = 0; jj < 8; jj++) {
                const short hi = bf16_hi(av[jj]);
                ah[jj] = hi;
                al[jj] = bf16_hi(av[jj] - bf16_tof(hi));
            }
            const int wo = kt * 32 + q * 8;
            const short8 bh0 = *(const short8*)(wsh + wrow0 + wo);
            const short8 bl0 = *(const short8*)(wsl + wrow0 + wo);
            const short8 bh1 = *(const short8*)(wsh + wrow1 + wo);
            const short8 bl1 = *(const short8*)(wsl + wrow1 + wo);

            acc0 = __builtin_amdgcn_mfma_f32_16x16x32_bf16(ah, bh0, acc0, 0, 0, 0);
            acc0 = __builtin_amdgcn_mfma_f32_16x16x32_bf16(al, bh0, acc0, 0, 0, 0);
            acc0 = __builtin_amdgcn_mfma_f32_16x16x32_bf16(ah, bl0, acc0, 0, 0, 0);
            acc1 = __builtin_amdgcn_mfma_f32_16x16x32_bf16(ah, bh1, acc1, 0, 0, 0);
            acc1 = __builtin_amdgcn_mfma_f32_16x16x32_bf16(al, bh1, acc1, 0, 0, 0);
            acc1 = __builtin_amdgcn_mfma_f32_16x16x32_bf16(ah, bl1, acc1, 0, 0, 0);
        }
#pragma unroll
        for (int r = 0; r < 4; ++r) {
            const int row = c * 64 + wave * 16 + q * 4 + r;
            gs[row * 32 + m]      = acc0[r];
            gs[row * 32 + 16 + m] = acc1[r];
        }
    }

    __syncthreads();                               // gi complete in LDS

    // ---- Phase A.5: backward direction = ONE GRU step on x[:,511], h0=0.
    //      30 gates x 8 lanes; x row + w rows are L2-hot.
    if (t < G3 * 8) {
        const int g = t >> 3, jj = t & 7;
        const float* __restrict__ xrow = xb + (size_t)(SEQ - 1) * EMB;
        float acc = 0.0f;
#pragma unroll
        for (int i = 0; i < 10; ++i) {
            const int k = jj * 4 + i * 32;
            if (k < EMB) {
                const float4 wv = *(const float4*)(w_ih_b + (size_t)g * EMB + k);
                const float4 xv = *(const float4*)(xrow + k);
                acc = fmaf(xv.x, wv.x, acc);
                acc = fmaf(xv.y, wv.y, acc);
                acc = fmaf(xv.z, wv.z, acc);
                acc = fmaf(xv.w, wv.w, acc);
            }
        }
        acc += __shfl_down(acc, 4, 8);
        acc += __shfl_down(acc, 2, 8);
        acc += __shfl_down(acc, 1, 8);
        if (jj == 0) gsum[g] = acc + b_ih_b[g];
    }
    __syncthreads();
    if (t < HID) {
        const float r = fsig(gsum[t] + b_hh_b[t]);
        const float z = fsig(gsum[HID + t] + b_hh_b[HID + t]);
        const float n = ftanh(fmaf(r, b_hh_b[2 * HID + t], gsum[2 * HID + t]));
        hbs[t] = (1.0f - z) * n;
    }
    __syncthreads();                               // hbs visible before scan exit
    if (t >= 64) return;

    // ---- Phase B: forward recurrence, 1 wave, gi already in LDS.
    const int j = t;
    const int jc = (j < HID) ? j : HID - 1;

    float wr[HID], wz[HID], wn[HID];
#pragma unroll
    for (int k = 0; k < HID; k++) {
        wr[k] = w_hh_f[jc * HID + k];
        wz[k] = w_hh_f[(HID + jc) * HID + k];
        wn[k] = w_hh_f[(2 * HID + jc) * HID + k];
    }
    const float br = b_hh_f[jc];
    const float bz = b_hh_f[HID + jc];
    const float bn = b_hh_f[2 * HID + jc];
    const float hbv = hbs[jc];

    float pr[PFD], pz[PFD], pn[PFD];
#pragma unroll
    for (int d = 0; d < PFD; d++) {
        pr[d] = gs[d * 32 + jc];
        pz[d] = gs[d * 32 + HID + jc];
        pn[d] = gs[d * 32 + 2 * HID + jc];
    }

    float h = 0.0f;
    float hs[HID];
#pragma unroll
    for (int k = 0; k < HID; k++) hs[k] = 0.0f;

    for (int tt = 0; tt < SEQ; tt += PFD) {
#pragma unroll
        for (int d = 0; d < PFD; d++) {
            const float ir = pr[d], iz = pz[d], in_ = pn[d];

            int tn = tt + d + PFD;
            if (tn >= SEQ) tn = SEQ - 1;
            const float* __restrict__ gp = gs + tn * 32;
            pr[d] = gp[jc];
            pz[d] = gp[HID + jc];
            pn[d] = gp[2 * HID + jc];

            // 2-accumulator dots: serial chain 5 FMAs instead of 10
            float ar0 = ir + br, ar1 = 0.0f;
            float az0 = iz + bz, az1 = 0.0f;
            float an0 = bn,      an1 = 0.0f;
#pragma unroll
            for (int k = 0; k < 5; k++) {
                ar0 = fmaf(wr[k], hs[k], ar0);
                az0 = fmaf(wz[k], hs[k], az0);
                an0 = fmaf(wn[k], hs[k], an0);
                ar1 = fmaf(wr[k + 5], hs[k + 5], ar1);
                az1 = fmaf(wz[k + 5], hs[k + 5], az1);
                an1 = fmaf(wn[k + 5], hs[k + 5], an1);
            }
            const float r = fsig(ar0 + ar1);
            const float z = fsig(az0 + az1);
            const float n = ftanh(fmaf(r, an0 + an1, in_));
            h = fmaf(z, h - n, n);                 // (1-z)*n + z*h

#pragma unroll
            for (int k = 0; k < HID; k++) hs[k] = rdlane(h, k);
        }
    }

    const float p = fmaf(w_lin[jc], h, w_lin[HID + jc] * hbv);
    float s = 0.0f;
#pragma unroll
    for (int k = 0; k < HID; k++) s += rdlane(p, k);
    if (j == 0) out[b] = s + b_lin[0];
}

// ---------------------------------------------------------------------------
extern "C" void kernel_launch(void* const* d_in, const int* in_sizes, int n_in,
                              void* d_out, int out_size, void* d_ws, size_t ws_size,
                              hipStream_t stream) {
    const float* x      = (const float*)d_in[0];
    const float* w_ih_f = (const float*)d_in[1];
    const float* w_hh_f = (const float*)d_in[2];
    const float* b_ih_f = (const float*)d_in[3];
    const float* b_hh_f = (const float*)d_in[4];
    const float* w_ih_b = (const float*)d_in[5];
    const float* w_hh_b = (const float*)d_in[6];   // unused: backward is one step, h0=0
    const float* b_ih_b = (const float*)d_in[7];
    const float* b_hh_b = (const float*)d_in[8];
    const float* w_lin  = (const float*)d_in[9];
    const float* b_lin  = (const float*)d_in[10];
    (void)w_hh_b; (void)in_sizes; (void)n_in; (void)out_size;
    (void)d_ws; (void)ws_size;                     // workspace intentionally unused

    k_fused<<<BATCH, 256, 0, stream>>>(x, w_ih_f, b_ih_f, w_hh_f, b_hh_f,
                                       w_ih_b, b_ih_b, b_hh_b, w_lin, b_lin,
                                       (float*)d_out);
}